// Round 8
// baseline (3688.681 us; speedup 1.0000x reference)
//
#include <hip/hip_runtime.h>
#include <hip/hip_bf16.h>
#include <stdint.h>

#define N_CELLS  512
#define N_PIX    25600
#define NBF      100      // n_bins_filter
#define MAXC     20
#define N_FRAMES 300
#define NBT      1500     // n_bins_total
#define N_INIT   100
#define T_STEPS  (NBT - N_INIT)   // 1400

#define K       4                  // steps per batch (one exchange per K steps)
#define NBATCH  (T_STEPS / K)      // 350
#define NSRC    (MAXC + 1)         // 21
#define NWG     64
#define CPW     8                  // distributed-partial cells per WG (1 per wave)
#define NROW    (CPW * NSRC)       // 168 ring rows per WG
#define SLOTS   104                // ring depth (time mod 104)

// ---------------- GEMM tiling ----------------
#define GT 64
#define GC 64
#define GK 64
#define KSPLIT 8
#define KCH (N_PIX / KSPLIT)      // 3200

// ============== GEMM partial: part[kb][t][c] = sum_{k in chunk} A[t,k]*B[c,k] ==============
__global__ __launch_bounds__(256) void gemm_partial_k(
        const float* __restrict__ A,   // input_frames [300][25600]
        const float* __restrict__ B,   // spat_filters [512][25600]
        float* __restrict__ part)      // [KSPLIT][300][512]
{
    __shared__ float As[GK][GT + 4];   // transposed: [k][row]
    __shared__ float Bs[GK][GC + 4];
    const int kb = blockIdx.x, tb = blockIdx.y, cb = blockIdx.z;
    const int tid = threadIdx.x;
    const int tx = tid & 15, ty = tid >> 4;
    const int t0 = tb * GT, c0 = cb * GC, k0 = kb * KCH;

    float acc[4][4];
    #pragma unroll
    for (int i = 0; i < 4; ++i)
        #pragma unroll
        for (int j = 0; j < 4; ++j) acc[i][j] = 0.f;

    for (int kc = 0; kc < KCH; kc += GK) {
        #pragma unroll
        for (int p = 0; p < 4; ++p) {
            const int r  = (tid >> 4) + p * 16;
            const int kk = (tid & 15) * 4;
            float4 av = make_float4(0.f, 0.f, 0.f, 0.f);
            if (t0 + r < N_FRAMES)
                av = *(const float4*)&A[(size_t)(t0 + r) * N_PIX + k0 + kc + kk];
            As[kk + 0][r] = av.x; As[kk + 1][r] = av.y;
            As[kk + 2][r] = av.z; As[kk + 3][r] = av.w;
            const float4 bv = *(const float4*)&B[(size_t)(c0 + r) * N_PIX + k0 + kc + kk];
            Bs[kk + 0][r] = bv.x; Bs[kk + 1][r] = bv.y;
            Bs[kk + 2][r] = bv.z; Bs[kk + 3][r] = bv.w;
        }
        __syncthreads();
        #pragma unroll
        for (int kk = 0; kk < GK; ++kk) {
            const float4 a4 = *(const float4*)&As[kk][ty * 4];
            const float4 b4 = *(const float4*)&Bs[kk][tx * 4];
            const float aa[4] = {a4.x, a4.y, a4.z, a4.w};
            const float bb[4] = {b4.x, b4.y, b4.z, b4.w};
            #pragma unroll
            for (int ii = 0; ii < 4; ++ii)
                #pragma unroll
                for (int jj = 0; jj < 4; ++jj)
                    acc[ii][jj] = fmaf(aa[ii], bb[jj], acc[ii][jj]);
        }
        __syncthreads();
    }
    #pragma unroll
    for (int ii = 0; ii < 4; ++ii) {
        const int t = t0 + ty * 4 + ii;
        if (t < N_FRAMES) {
            #pragma unroll
            for (int jj = 0; jj < 4; ++jj)
                part[(size_t)kb * (N_FRAMES * N_CELLS) + (size_t)t * N_CELLS + c0 + tx * 4 + jj] = acc[ii][jj];
        }
    }
}

// ============== reduce split-K partials ==============
__global__ void reduce_part_k(const float* __restrict__ part, float* __restrict__ spat) {
    int i = blockIdx.x * 256 + threadIdx.x;
    if (i < N_FRAMES * N_CELLS) {
        float s = 0.f;
        #pragma unroll
        for (int kb = 0; kb < KSPLIT; ++kb) s += part[(size_t)kb * (N_FRAMES * N_CELLS) + i];
        spat[i] = s;
    }
}

// ============== stim[t][c] = bias[c] + sum_k fw[t,k]*spat[fs[t,k]][c] ==============
__global__ void stim_k(const float* __restrict__ spat, const float* __restrict__ bias,
                       const float* __restrict__ fw, const int* __restrict__ fs,
                       float* __restrict__ stimb) {
    int i = blockIdx.x * 256 + threadIdx.x;
    if (i < NBT * N_CELLS) {
        const int t = i >> 9, c = i & (N_CELLS - 1);
        const int t2 = t * 2;
        float v = bias[c];
        v = fmaf(fw[t2],     spat[(size_t)fs[t2]     * N_CELLS + c], v);
        v = fmaf(fw[t2 + 1], spat[(size_t)fs[t2 + 1] * N_CELLS + c], v);
        stimb[i] = v;
    }
}

// ============== copy initial spikes into out[c][0..99] ==============
__global__ void copy_init_k(const float* __restrict__ ini, float* __restrict__ out) {
    int i = blockIdx.x * 256 + threadIdx.x;
    if (i < N_CELLS * N_INIT) {
        const int c = i / N_INIT;
        const int j = i - c * N_INIT;
        out[(size_t)c * NBT + j] = ini[i];
    }
}

__device__ __forceinline__ int wrapm(int t) {          // t >= -208
    return (t + 2 * SLOTS) % SLOTS;
}
__device__ __forceinline__ unsigned short f2bf_bits(float v) {
    __hip_bfloat16 h = __float2bfloat16(v);
    return *reinterpret_cast<unsigned short*>(&h);
}
__device__ __forceinline__ float bfbits2f(uint32_t b) {
    return __uint_as_float((b & 0xffffu) << 16);
}
__device__ __forceinline__ unsigned long long ald64(const unsigned long long* p) {
    return __hip_atomic_load(p, __ATOMIC_RELAXED, __HIP_MEMORY_SCOPE_AGENT);
}
__device__ __forceinline__ void ast64(unsigned long long* p, unsigned long long v) {
    __hip_atomic_store(p, v, __ATOMIC_RELAXED, __HIP_MEMORY_SCOPE_AGENT);
}

// ============== batched redundant scan ==============
// Near part (lags 1..4): every WG computes ALL 512 cells redundantly (thread=cell),
//   bitwise-identical across WGs -> no exchange.
// Far part (lags 5..100): distributed (wave=cell, lane=lag), exchanged as per-step
//   partials, once per K=4 steps. Partial word: u64 = (tag=batch+1)<<32 | f32 bits.
//   Parity double-buffer P[2][K][512] -> overwrite distance 2 batches (safe).
__global__ __launch_bounds__(512) void scan_k(
        const float* __restrict__ stimb,  // [1500][512]
        const float* __restrict__ cf,     // [512][20][100]
        const float* __restrict__ ff,     // [512][100]
        const int*   __restrict__ sel,    // [512][20]
        const float* __restrict__ ini,    // [512][100]
        unsigned long long* __restrict__ P,  // [2][K][512] tagged partials
        float* __restrict__ out)          // [512][1500]
{
    __shared__ unsigned short win[NROW][SLOTS];   // sources' bf16 history (this WG's 8 cells)
    __shared__ float ybatch[K][N_CELLS];          // f32 spikes of the current batch

    const int tid  = threadIdx.x;
    const int wave = tid >> 6;
    const int lane = tid & 63;
    const int wg   = blockIdx.x;
    const int cellB = wg * CPW + wave;            // role-B cell (distributed partial)

    // ---- role A (cell = tid): near coefs (lags 1..4, f32 regs) + source ids ----
    int   srcA[NSRC];
    float lc0[NSRC], lc1[NSRC], lc2[NSRC], lc3[NSRC];
    #pragma unroll
    for (int m = 0; m < NSRC; ++m) {
        const int s = (m < MAXC) ? sel[tid * MAXC + m] : tid;
        const float* f = (m < MAXC) ? (cf + (size_t)(tid * MAXC + m) * NBF)
                                    : (ff + (size_t)tid * NBF);
        srcA[m] = s;
        lc0[m] = f[99]; lc1[m] = f[98]; lc2[m] = f[97]; lc3[m] = f[96];
    }

    // ---- role B (cell = cellB): far coefs, lane <-> lag (lane+5, lane+69) ----
    float c1v[NSRC], c2v[NSRC];
    #pragma unroll
    for (int m = 0; m < NSRC; ++m) {
        const float* f = (m < MAXC) ? (cf + (size_t)(cellB * MAXC + m) * NBF)
                                    : (ff + (size_t)cellB * NBF);
        c1v[m] = f[95 - lane];                        // lag lane+5  -> idx 95..32
        c2v[m] = (lane <= 31) ? f[31 - lane] : 0.f;   // lag lane+69 -> idx 31..0
    }

    // ---- ingest duty: thread t<168 owns ring row t ----
    int srcRow = 0;
    if (tid < NROW) {
        const int w2 = tid / NSRC, m2 = tid - w2 * NSRC;
        const int cb2 = wg * CPW + w2;
        srcRow = (m2 < MAXC) ? sel[cb2 * MAXC + m2] : cb2;
        // ring init: times -100..-1 -> slots 4..103
        for (int b = 0; b < N_INIT; ++b)
            win[tid][b + 4] = f2bf_bits(ini[(size_t)srcRow * N_INIT + b]);
    }
    __syncthreads();

    // ---- acc prologue: pushes from times -1..-4 (f32 from ini) ----
    float aC0 = 0.f, aC1 = 0.f, aC2 = 0.f, aC3 = 0.f;
    float aN0 = 0.f, aN1 = 0.f, aN2 = 0.f, aN3 = 0.f;
    #pragma unroll
    for (int m = 0; m < NSRC; ++m) {
        const float* yb = ini + (size_t)srcA[m] * N_INIT;
        const float y1 = yb[99], y2 = yb[98], y3 = yb[97], y4 = yb[96];
        aC0 += lc0[m]*y1 + lc1[m]*y2 + lc2[m]*y3 + lc3[m]*y4;
        aC1 += lc1[m]*y1 + lc2[m]*y2 + lc3[m]*y3;
        aC2 += lc2[m]*y1 + lc3[m]*y2;
        aC3 += lc3[m]*y1;
    }

    // ---- far-partial helper: 4 partials for batch starting at i0n, slot bases sp1/sp2 ----
    auto partial4 = [&](int sp1, int sp2, float* pout) {
        #pragma unroll
        for (int d = 0; d < K; ++d) {
            int a1 = sp1 + d; if (a1 >= SLOTS) a1 -= SLOTS;
            int a2 = sp2 + d; if (a2 >= SLOTS) a2 -= SLOTS;
            float p = 0.f;
            #pragma unroll
            for (int m = 0; m < NSRC; ++m) {
                const int row = wave * NSRC + m;
                p = fmaf(bfbits2f(win[row][a1]), c1v[m], p);
                p = fmaf(bfbits2f(win[row][a2]), c2v[m], p);
            }
            #pragma unroll
            for (int off = 32; off; off >>= 1) p += __shfl_xor(p, off, 64);
            pout[d] = p;
        }
    };

    // slot bases for partial of batch 0 (i0'=0): wrap(-5-lane), wrap(-69-lane)
    int sp1 = wrapm(-5 - lane);
    int sp2 = (lane <= 31) ? wrapm(-69 - lane) : sp1;

    // ---- pre-loop: compute + push partials for batch 0 (tag 1, parity 0) ----
    {
        float pw[K];
        partial4(sp1, sp2, pw);
        if (lane == 0) {
            #pragma unroll
            for (int d = 0; d < K; ++d)
                ast64(&P[(size_t)d * N_CELLS + cellB],
                      (1ull << 32) | (unsigned long long)__float_as_uint(pw[d]));
        }
    }

    int sI = 0;   // ring slot of time i0

    for (int b = 0; b < NBATCH; ++b) {
        const int i0 = b * K;

        // stim prefetch (coalesced)
        const float st0 = stimb[(size_t)(99 + i0) * N_CELLS + tid];
        const float st1 = stimb[(size_t)(100 + i0) * N_CELLS + tid];
        const float st2 = stimb[(size_t)(101 + i0) * N_CELLS + tid];
        const float st3 = stimb[(size_t)(102 + i0) * N_CELLS + tid];

        // ---- poll own cell's 4 partials (per-thread gate) ----
        const unsigned long long* Pb = P + (size_t)(b & 1) * (K * N_CELLS);
        unsigned long long v0, v1, v2, v3;
        const uint32_t tg = (uint32_t)(b + 1);
        do {
            v0 = ald64(Pb + tid);
            v1 = ald64(Pb + N_CELLS + tid);
            v2 = ald64(Pb + 2 * N_CELLS + tid);
            v3 = ald64(Pb + 3 * N_CELLS + tid);
        } while ((uint32_t)(v0 >> 32) != tg || (uint32_t)(v1 >> 32) != tg ||
                 (uint32_t)(v2 >> 32) != tg || (uint32_t)(v3 >> 32) != tg);
        const float pf0 = __uint_as_float((uint32_t)v0);
        const float pf1 = __uint_as_float((uint32_t)v1);
        const float pf2 = __uint_as_float((uint32_t)v2);
        const float pf3 = __uint_as_float((uint32_t)v3);

        float y0, y1, y2, y3;

        // ===== step 0 =====
        { const float g = st0 + pf0 + aC0; y0 = 1.f / (1.f + __expf(-g)); ybatch[0][tid] = y0; }
        __syncthreads();
        #pragma unroll
        for (int m = 0; m < NSRC; ++m) {
            const float yv = ybatch[0][srcA[m]];
            aC1 = fmaf(lc0[m], yv, aC1); aC2 = fmaf(lc1[m], yv, aC2);
            aC3 = fmaf(lc2[m], yv, aC3); aN0 = fmaf(lc3[m], yv, aN0);
        }
        // ===== step 1 =====
        { const float g = st1 + pf1 + aC1; y1 = 1.f / (1.f + __expf(-g)); ybatch[1][tid] = y1; }
        __syncthreads();
        #pragma unroll
        for (int m = 0; m < NSRC; ++m) {
            const float yv = ybatch[1][srcA[m]];
            aC2 = fmaf(lc0[m], yv, aC2); aC3 = fmaf(lc1[m], yv, aC3);
            aN0 = fmaf(lc2[m], yv, aN0); aN1 = fmaf(lc3[m], yv, aN1);
        }
        // ===== step 2 =====
        { const float g = st2 + pf2 + aC2; y2 = 1.f / (1.f + __expf(-g)); ybatch[2][tid] = y2; }
        __syncthreads();
        #pragma unroll
        for (int m = 0; m < NSRC; ++m) {
            const float yv = ybatch[2][srcA[m]];
            aC3 = fmaf(lc0[m], yv, aC3); aN0 = fmaf(lc1[m], yv, aN0);
            aN1 = fmaf(lc2[m], yv, aN1); aN2 = fmaf(lc3[m], yv, aN2);
        }
        // ===== step 3 =====
        { const float g = st3 + pf3 + aC3; y3 = 1.f / (1.f + __expf(-g)); ybatch[3][tid] = y3; }
        __syncthreads();
        #pragma unroll
        for (int m = 0; m < NSRC; ++m) {
            const float yv = ybatch[3][srcA[m]];
            aN0 = fmaf(lc0[m], yv, aN0); aN1 = fmaf(lc1[m], yv, aN1);
            aN2 = fmaf(lc2[m], yv, aN2); aN3 = fmaf(lc3[m], yv, aN3);
        }

        // out: only the owner WG writes its 8 cells (cells wg*8..wg*8+7 = threads with tid>>3==wg)
        if ((tid >> 3) == wg) {
            float* o = out + (size_t)tid * NBT + N_INIT + i0;
            o[0] = y0; o[1] = y1; o[2] = y2; o[3] = y3;
        }

        // rotate accumulators (pushes targeting next batch -> current)
        aC0 = aN0; aC1 = aN1; aC2 = aN2; aC3 = aN3;
        aN0 = 0.f; aN1 = 0.f; aN2 = 0.f; aN3 = 0.f;

        if (b + 1 < NBATCH) {
            // ---- ingest batch spikes into ring (bf16) ----
            if (tid < NROW) {
                int s0 = sI;                 int s1s = sI + 1; if (s1s >= SLOTS) s1s -= SLOTS;
                int s2s = sI + 2; if (s2s >= SLOTS) s2s -= SLOTS;
                int s3s = sI + 3; if (s3s >= SLOTS) s3s -= SLOTS;
                win[tid][s0]  = f2bf_bits(ybatch[0][srcRow]);
                win[tid][s1s] = f2bf_bits(ybatch[1][srcRow]);
                win[tid][s2s] = f2bf_bits(ybatch[2][srcRow]);
                win[tid][s3s] = f2bf_bits(ybatch[3][srcRow]);
            }
            sI += K; if (sI >= SLOTS) sI -= SLOTS;
            __syncthreads();

            // ---- far partials for batch b+1; push (tag b+2, parity (b+1)&1) ----
            sp1 += K; if (sp1 >= SLOTS) sp1 -= SLOTS;
            sp2 += K; if (sp2 >= SLOTS) sp2 -= SLOTS;
            float pw[K];
            partial4(sp1, sp2, pw);
            if (lane == 0) {
                unsigned long long* Pn = P + (size_t)((b + 1) & 1) * (K * N_CELLS);
                const unsigned long long tga = ((unsigned long long)(b + 2)) << 32;
                #pragma unroll
                for (int d = 0; d < K; ++d)
                    ast64(&Pn[(size_t)d * N_CELLS + cellB],
                          tga | (unsigned long long)__float_as_uint(pw[d]));
            }
        }
    }
}

extern "C" void kernel_launch(void* const* d_in, const int* in_sizes, int n_in,
                              void* d_out, int out_size, void* d_ws, size_t ws_size,
                              hipStream_t stream) {
    const float* ini    = (const float*)d_in[0];   // initial_spikes [512][100]
    const float* frames = (const float*)d_in[1];   // input_frames  [300][25600]
    const float* sfil   = (const float*)d_in[2];   // spat_filters  [512][25600]
    const float* ff     = (const float*)d_in[3];   // feedback_filters [512][100]
    const float* cf     = (const float*)d_in[4];   // coupling_filters [512][20][100]
    const float* bias   = (const float*)d_in[5];   // [512][1]
    const float* fw     = (const float*)d_in[6];   // forward_weights [1500][2]
    const int*   sel    = (const int*)d_in[7];     // coupled_sel [512][20]
    const int*   fs     = (const int*)d_in[8];     // forward_sel [1500][2]
    float* out = (float*)d_out;
    float* ws  = (float*)d_ws;

    // ws layout (floats): spat@0 (153600) | stimb@153600 (768000) | P@921600 (8192 f-equiv) |
    //                     part@153600 (KSPLIT*153600, overlaps stimb+P; dead after reduce)
    float* spat  = ws;
    float* stimb = ws + 153600;
    unsigned long long* P = (unsigned long long*)(ws + 153600 + 768000);
    float* part  = ws + 153600;

    hipLaunchKernelGGL(gemm_partial_k,
                       dim3(KSPLIT, (N_FRAMES + GT - 1) / GT, N_CELLS / GC), dim3(256), 0, stream,
                       frames, sfil, part);
    hipLaunchKernelGGL(reduce_part_k, dim3((N_FRAMES * N_CELLS + 255) / 256), dim3(256), 0, stream, part, spat);
    hipLaunchKernelGGL(stim_k, dim3((NBT * N_CELLS + 255) / 256), dim3(256), 0, stream, spat, bias, fw, fs, stimb);
    hipMemsetAsync(P, 0, (size_t)2 * K * N_CELLS * sizeof(unsigned long long), stream);
    hipLaunchKernelGGL(copy_init_k, dim3((N_CELLS * N_INIT + 255) / 256), dim3(256), 0, stream, ini, out);
    hipLaunchKernelGGL(scan_k, dim3(NWG), dim3(512), 0, stream,
                       stimb, cf, ff, sel, ini, P, out);
}

// Round 9
// 2083.371 us; speedup vs baseline: 1.7705x; 1.7705x over previous
//
#include <hip/hip_runtime.h>
#include <hip/hip_bf16.h>
#include <stdint.h>

#define N_CELLS  512
#define N_PIX    25600
#define NBF      100      // n_bins_filter
#define MAXC     20
#define N_FRAMES 300
#define NBT      1500     // n_bins_total
#define N_INIT   100
#define T_STEPS  (NBT - N_INIT)   // 1400

#define RING   104        // logical ring (time mod RING)
#define RSTR   105        // LDS storage stride (odd -> conflict-free column writes)
#define NWG    64
#define CPW    (N_CELLS / NWG)    // 8 cells per WG
#define SCAN_THREADS (CPW * 64)   // 512
#define XDEPTH 8                  // exchange ring depth (producer lead <= ~2)

// ---------------- MFMA GEMM tiling ----------------
#define MT 64
#define NT 64
#define KT 32
#define KSPLIT 8
#define KCH (N_PIX / KSPLIT)      // 3200
#define APAD 8                    // LDS row pad (shorts)

typedef short    bf16x8 __attribute__((ext_vector_type(8)));
typedef float    f32x4  __attribute__((ext_vector_type(4)));
typedef unsigned short u16x4 __attribute__((ext_vector_type(4)));

// ============== MFMA GEMM partial: part[kb][t][c] = sum_{k in chunk} A[t,k]*B[c,k] ==============
// fp32 inputs converted to bf16 during LDS staging; fp32 MFMA accumulate.
__global__ __launch_bounds__(256) void gemm_mfma_k(
        const float* __restrict__ A,   // input_frames [300][25600]
        const float* __restrict__ B,   // spat_filters [512][25600]
        float* __restrict__ part)      // [KSPLIT][300][512]
{
    __shared__ __hip_bfloat16 As[MT][KT + APAD];
    __shared__ __hip_bfloat16 Bs[NT][KT + APAD];

    const int kb = blockIdx.x, tb = blockIdx.y, cb = blockIdx.z;
    const int tid  = threadIdx.x;
    const int wave = tid >> 6;          // 0..3 -> M sub-strip
    const int lane = tid & 63;
    const int t0 = tb * MT, c0 = cb * NT, k0 = kb * KCH;

    const int srow = tid >> 3;          // 0..31 (stage rows srow, srow+32)
    const int sk4  = (tid & 7) * 4;     // k offset 0,4,..,28

    f32x4 acc[4];
    #pragma unroll
    for (int n = 0; n < 4; ++n) acc[n] = (f32x4){0.f, 0.f, 0.f, 0.f};

    const int frow = wave * 16 + (lane & 15);   // fragment row within tile
    const int fk   = (lane >> 4) * 8;           // fragment k offset (0,8,16,24)

    for (int kc = 0; kc < KCH; kc += KT) {
        // ---- stage A,B (fp32 -> bf16) ----
        #pragma unroll
        for (int h = 0; h < 2; ++h) {
            const int r = srow + h * 32;
            // A row (guard M=300)
            float4 av = make_float4(0.f, 0.f, 0.f, 0.f);
            if (t0 + r < N_FRAMES)
                av = *(const float4*)&A[(size_t)(t0 + r) * N_PIX + k0 + kc + sk4];
            u16x4 ap;
            {
                __hip_bfloat16 b0 = __float2bfloat16(av.x), b1 = __float2bfloat16(av.y);
                __hip_bfloat16 b2 = __float2bfloat16(av.z), b3 = __float2bfloat16(av.w);
                ap[0] = *(unsigned short*)&b0; ap[1] = *(unsigned short*)&b1;
                ap[2] = *(unsigned short*)&b2; ap[3] = *(unsigned short*)&b3;
            }
            *(u16x4*)&As[r][sk4] = ap;
            // B row
            const float4 bv = *(const float4*)&B[(size_t)(c0 + r) * N_PIX + k0 + kc + sk4];
            u16x4 bp;
            {
                __hip_bfloat16 b0 = __float2bfloat16(bv.x), b1 = __float2bfloat16(bv.y);
                __hip_bfloat16 b2 = __float2bfloat16(bv.z), b3 = __float2bfloat16(bv.w);
                bp[0] = *(unsigned short*)&b0; bp[1] = *(unsigned short*)&b1;
                bp[2] = *(unsigned short*)&b2; bp[3] = *(unsigned short*)&b3;
            }
            *(u16x4*)&Bs[r][sk4] = bp;
        }
        __syncthreads();

        // ---- fragments + 4 MFMA ----
        const bf16x8 af = *(const bf16x8*)&As[frow][fk];
        #pragma unroll
        for (int n = 0; n < 4; ++n) {
            const bf16x8 bf = *(const bf16x8*)&Bs[n * 16 + (lane & 15)][fk];
            acc[n] = __builtin_amdgcn_mfma_f32_16x16x32_bf16(af, bf, acc[n], 0, 0, 0);
        }
        __syncthreads();
    }

    // ---- epilogue: C mapping col=lane&15, row=(lane>>4)*4+reg ----
    #pragma unroll
    for (int n = 0; n < 4; ++n) {
        const int c = c0 + n * 16 + (lane & 15);
        #pragma unroll
        for (int r = 0; r < 4; ++r) {
            const int t = t0 + wave * 16 + (lane >> 4) * 4 + r;
            if (t < N_FRAMES)
                part[(size_t)kb * (N_FRAMES * N_CELLS) + (size_t)t * N_CELLS + c] = acc[n][r];
        }
    }
}

// ============== reduce split-K partials ==============
__global__ void reduce_part_k(const float* __restrict__ part, float* __restrict__ spat) {
    int i = blockIdx.x * 256 + threadIdx.x;
    if (i < N_FRAMES * N_CELLS) {
        float s = 0.f;
        #pragma unroll
        for (int kb = 0; kb < KSPLIT; ++kb) s += part[(size_t)kb * (N_FRAMES * N_CELLS) + i];
        spat[i] = s;
    }
}

// ============== stim[t][c] = bias[c] + sum_k fw[t,k]*spat[fs[t,k]][c] ==============
__global__ void stim_k(const float* __restrict__ spat, const float* __restrict__ bias,
                       const float* __restrict__ fw, const int* __restrict__ fs,
                       float* __restrict__ stimb) {
    int i = blockIdx.x * 256 + threadIdx.x;
    if (i < NBT * N_CELLS) {
        const int t = i >> 9, c = i & (N_CELLS - 1);
        const int t2 = t * 2;
        float v = bias[c];
        v = fmaf(fw[t2],     spat[(size_t)fs[t2]     * N_CELLS + c], v);
        v = fmaf(fw[t2 + 1], spat[(size_t)fs[t2 + 1] * N_CELLS + c], v);
        stimb[i] = v;
    }
}

// ============== copy initial spikes into out[c][0..99] ==============
__global__ void copy_init_k(const float* __restrict__ ini, float* __restrict__ out) {
    int i = blockIdx.x * 256 + threadIdx.x;
    if (i < N_CELLS * N_INIT) {
        const int c = i / N_INIT;
        const int j = i - c * N_INIT;
        out[(size_t)c * NBT + j] = ini[i];
    }
}

__device__ __forceinline__ int wrap_slot(int t) {
    int s = t % RING;
    return (s < 0) ? s + RING : s;
}

// ============== persistent scan (R2, verbatim): 64 WGs, wave-per-cell, tagged-word exchange ==============
// Exchange word for step s: (uint64)(s+1) << 32 | f32_bits(spike).
__global__ __launch_bounds__(SCAN_THREADS) void scan_k(
        const float* __restrict__ stimb,  // [1500][512]
        const float* __restrict__ cf,     // [512][20][100]
        const float* __restrict__ ff,     // [512][100]
        const int*   __restrict__ sel,    // [512][20]
        const float* __restrict__ ini,    // [512][100]
        unsigned long long* __restrict__ X64,  // [XDEPTH][512] tagged exchange
        float* __restrict__ out)          // [512][1500]
{
    __shared__ __hip_bfloat16 win[N_CELLS][RSTR];   // spike-history ring, all cells
    __shared__ float newspike[N_CELLS];             // f32 spikes of time i-1
    __shared__ int   lag1src[CPW][32];
    __shared__ float lag1coef[CPW][32];

    const int wg   = blockIdx.x;
    const int tid  = threadIdx.x;
    const int wave = tid >> 6;
    const int lane = tid & 63;
    const int cell = wg * CPW + wave;

    // ---- per-lane static coefficients for the lag>=2 partial:
    //      lane -> lag lane+2 (c1v) and lag lane+66 (c2v, lane<=34) ----
    int   srcm[MAXC + 1];
    float c1v[MAXC + 1], c2v[MAXC + 1];
    #pragma unroll
    for (int m = 0; m <= MAXC; ++m) {
        const int s = (m < MAXC) ? sel[cell * MAXC + m] : cell;
        const float* f = (m < MAXC) ? (cf + (size_t)(cell * MAXC + m) * NBF)
                                    : (ff + (size_t)cell * NBF);
        srcm[m] = s;
        c1v[m]  = f[98 - lane];                        // lag lane+2 -> idx 98..35
        c2v[m]  = (lane <= 34) ? f[34 - lane] : 0.f;   // lag lane+66 -> idx 34..0
        if (lane == m) {                               // lag-1 tables (static index)
            lag1src[wave][m]  = s;
            lag1coef[wave][m] = f[NBF - 1];
        }
    }

    // ---- window init: zero ring, then initial spikes at times -100..-1 ----
    {
        __hip_bfloat16* wf = &win[0][0];
        for (int i = tid; i < N_CELLS * RSTR; i += SCAN_THREADS) wf[i] = __float2bfloat16(0.f);
        __syncthreads();
        for (int i = tid; i < N_CELLS * N_INIT; i += SCAN_THREADS) {
            const int c = i / N_INIT;
            const int b = i - c * N_INIT;
            win[c][wrap_slot(b - N_INIT)] = __float2bfloat16(ini[i]);
        }
    }
    __syncthreads();

    // slots for the partial (lags >=2) of the NEXT step to be computed:
    // pre-loop computes partial for step 0: lag lane+2 -> time -(lane+2)
    int slotp1 = wrap_slot(-2 - lane);
    int slotp2 = wrap_slot(-66 - lane);
    int slotw  = RING - 1;                 // slot(time i-1) used from i=1

    const float ini_last = ini[tid * N_INIT + (N_INIT - 1)];   // y_{-1}[tid]

    float stim_next = 0.f;
    if (lane == 0) stim_next = stimb[(size_t)(N_INIT - 1) * N_CELLS + cell];

    // partial_0 (lags 2..100 of step 0)
    float partial;
    {
        float p = 0.f;
        #pragma unroll
        for (int m = 0; m <= MAXC; ++m) {
            const float w1 = __bfloat162float(win[srcm[m]][slotp1]);
            const float w2 = __bfloat162float(win[srcm[m]][slotp2]);
            p = fmaf(w1, c1v[m], p);
            p = fmaf(w2, c2v[m], p);
        }
        #pragma unroll
        for (int off = 32; off > 0; off >>= 1) p += __shfl_xor(p, off, 64);
        partial = p;
    }

    for (int i = 0; i < T_STEPS; ++i) {
        // ---- 1. obtain y_{i-1}[tid] ----
        float val;
        if (i > 0) {
            const unsigned long long* wp = &X64[(size_t)((i - 1) & (XDEPTH - 1)) * N_CELLS + tid];
            unsigned long long w;
            do {
                w = __hip_atomic_load(wp, __ATOMIC_RELAXED, __HIP_MEMORY_SCOPE_AGENT);
            } while ((unsigned)(w >> 32) != (unsigned)i);
            val = __uint_as_float((unsigned)w);
        } else {
            val = ini_last;
        }

        // ---- 2. publish to LDS ----
        newspike[tid] = val;
        win[tid][slotw] = __float2bfloat16(val);
        __syncthreads();

        // ---- 3. critical lag-1 terms + sigmoid + post ----
        float term = 0.f;
        if (lane <= MAXC) {
            term = newspike[lag1src[wave][lane]] * lag1coef[wave][lane];
        }
        #pragma unroll
        for (int off = 16; off > 0; off >>= 1) term += __shfl_xor(term, off, 32);

        if (lane == 0) {
            const float g = stim_next + partial + term;
            const float s = 1.f / (1.f + __expf(-g));
            const unsigned long long pw =
                ((unsigned long long)(unsigned)(i + 1) << 32) |
                (unsigned long long)__float_as_uint(s);
            __hip_atomic_store(&X64[(size_t)(i & (XDEPTH - 1)) * N_CELLS + cell], pw,
                               __ATOMIC_RELAXED, __HIP_MEMORY_SCOPE_AGENT);
            out[(size_t)cell * NBT + N_INIT + i] = s;
        }

        // ---- 4. advance slots; compute partial for step i+1 (hidden under exchange) ----
        slotw  = (slotw  + 1 == RING) ? 0 : slotw  + 1;
        slotp1 = (slotp1 + 1 == RING) ? 0 : slotp1 + 1;
        slotp2 = (slotp2 + 1 == RING) ? 0 : slotp2 + 1;

        if (lane == 0 && i + 1 < T_STEPS)
            stim_next = stimb[(size_t)(N_INIT + i) * N_CELLS + cell];

        float p = 0.f;
        #pragma unroll
        for (int m = 0; m <= MAXC; ++m) {
            const float w1 = __bfloat162float(win[srcm[m]][slotp1]);
            const float w2 = __bfloat162float(win[srcm[m]][slotp2]);
            p = fmaf(w1, c1v[m], p);
            p = fmaf(w2, c2v[m], p);
        }
        #pragma unroll
        for (int off = 32; off > 0; off >>= 1) p += __shfl_xor(p, off, 64);
        partial = p;
    }
}

extern "C" void kernel_launch(void* const* d_in, const int* in_sizes, int n_in,
                              void* d_out, int out_size, void* d_ws, size_t ws_size,
                              hipStream_t stream) {
    const float* ini    = (const float*)d_in[0];   // initial_spikes [512][100]
    const float* frames = (const float*)d_in[1];   // input_frames  [300][25600]
    const float* sfil   = (const float*)d_in[2];   // spat_filters  [512][25600]
    const float* ff     = (const float*)d_in[3];   // feedback_filters [512][100]
    const float* cf     = (const float*)d_in[4];   // coupling_filters [512][20][100]
    const float* bias   = (const float*)d_in[5];   // [512][1]
    const float* fw     = (const float*)d_in[6];   // forward_weights [1500][2]
    const int*   sel    = (const int*)d_in[7];     // coupled_sel [512][20]
    const int*   fs     = (const int*)d_in[8];     // forward_sel [1500][2]
    float* out = (float*)d_out;
    float* ws  = (float*)d_ws;

    // ws layout (floats):
    //   spat  @ 0       (153600)
    //   stimb @ 153600  (768000)
    //   X64   @ 921600  (XDEPTH*512 u64 = 8192 floats)
    //   part  @ 153600  (KSPLIT*153600 = 1228800, overlaps stimb+X64; dead after reduce)
    float* spat  = ws;
    float* stimb = ws + 153600;
    unsigned long long* X64 = (unsigned long long*)(ws + 153600 + 768000);
    float* part  = ws + 153600;

    hipLaunchKernelGGL(gemm_mfma_k,
                       dim3(KSPLIT, (N_FRAMES + MT - 1) / MT, N_CELLS / NT), dim3(256), 0, stream,
                       frames, sfil, part);
    hipLaunchKernelGGL(reduce_part_k, dim3((N_FRAMES * N_CELLS + 255) / 256), dim3(256), 0, stream, part, spat);
    hipLaunchKernelGGL(stim_k, dim3((NBT * N_CELLS + 255) / 256), dim3(256), 0, stream, spat, bias, fw, fs, stimb);
    hipMemsetAsync(X64, 0, (size_t)XDEPTH * N_CELLS * sizeof(unsigned long long), stream);
    hipLaunchKernelGGL(copy_init_k, dim3((N_CELLS * N_INIT + 255) / 256), dim3(256), 0, stream, ini, out);
    hipLaunchKernelGGL(scan_k, dim3(NWG), dim3(SCAN_THREADS), 0, stream,
                       stimb, cf, ff, sel, ini, X64, out);
}